// Round 9
// baseline (454.151 us; speedup 1.0000x reference)
//
#include <hip/hip_runtime.h>

// Problem constants (fixed by the reference)
#define T_    2048
#define N_    1024
#define MC_   512
#define KF_   20
#define M_    5
#define J_    (KF_ * MC_)      // 10240
#define NSEG  16
#define SEGLEN (T_ / NSEG)     // 128
#define NIT   2                // Neumann iterations (err ~ ||L||^3 << bf16 noise)

typedef unsigned short u16;
typedef __attribute__((ext_vector_type(8))) __bf16 bf16v;          // MFMA A/B frag
typedef __attribute__((ext_vector_type(4))) float  f32x4;          // MFMA C/D frag
typedef __attribute__((ext_vector_type(8))) unsigned short u16x8;

__device__ inline u16 f2bf(float f) {                      // RNE f32 -> bf16
    unsigned u = __float_as_uint(f);
    u += 0x7fff + ((u >> 16) & 1);
    return (u16)(u >> 16);
}
__device__ inline float bf2f(u16 v) { return __uint_as_float((unsigned)v << 16); }

__device__ inline void gload16(const void* g, void* l) {   // 16B global -> LDS (lane*16 dest)
    __builtin_amdgcn_global_load_lds((const __attribute__((address_space(1))) void*)g,
                                     (__attribute__((address_space(3))) void*)l, 16, 0, 0);
}

// ---------------------------------------------------------------------------
// bf16 MFMA GEMM, TN form: C[m,n] = alpha * sum_k A[m,k]*B[n,k]
// 256x256 tile, 8 waves (wr=wv>>1: 64-row band; wc=wv&1: 128-col band;
// acc[4][8] frags of 16x16x32).
// DEEP-RING PIPELINE (T3+T4, r8 post-mortem): K processed in halves of 32
// (= one MFMA K-depth). LDS = 4-slot ring per matrix (4 x 256x32x2B = 64KB,
// 128KB total). Staged 3 halves ahead (12 wave-loads in flight). Per half:
//   s_waitcnt vmcnt(8)   <- only the OLDEST half must arrive; 2 halves stay
//                           in flight ACROSS the barrier (no drain-convoy)
//   s_barrier            <- collective: slot h fully written
//   issue half h+3 into slot (h+3)&3 (= (h-1)&3; its readers all passed
//                           this barrier -> single-barrier ring is race-free)
//   12 ds_read_b128 + 2x16 MFMA (setprio around MFMA: phase-split exists now)
// Epilogue: vmcnt literals 8 -> 4 -> 0. NH = Kc/32 >= 2 for all launches.
// LDS swizzle (64B rows): chunk ch (0..3) XORed with ((row>>1)&3) on the
// GLOBAL SOURCE (LDS dest linear, rule #21) and identically on ds_read:
// bank-quads 0,4,1,5,2,6,3,7 across 8 rows -> conflict-free (2-way alias free).
// Cp set: grid.z splits K; bf16 partials to Cp[z]. else: +Add, write Cf/Cb.
// Block ids chunk-swizzled across 8 XCDs (bijective; total%8==0 always here).
// ---------------------------------------------------------------------------
__global__ __launch_bounds__(512) void gemm_tn(
    const u16* __restrict__ A, const u16* __restrict__ B,
    const float* __restrict__ Add, float* __restrict__ Cf,
    u16* __restrict__ Cb, u16* __restrict__ Cp,
    int Mdim, int Ndim, int Kdim, float alpha)
{
    __shared__ u16 As[4][256 * 32];   // 16 KB per slot
    __shared__ u16 Bs[4][256 * 32];   // total 128 KB (1 block/CU, 8 waves)

    // ---- XCD chunk swizzle (T1, bijective since total%8==0) ----
    const int gx = gridDim.x, gy = gridDim.y;
    const int total = gx * gy * gridDim.z;
    int lin = blockIdx.x + gx * (blockIdx.y + gy * blockIdx.z);
    lin = (lin & 7) * (total >> 3) + (lin >> 3);
    int bx, by, bz;
    if (gx <= gy) { bx = lin % gx; int r = lin / gx; by = r % gy; bz = r / gy; }
    else          { by = lin % gy; int r = lin / gy; bx = r % gx; bz = r / gx; }

    const int tid = threadIdx.x;
    const int wv = tid >> 6, ln = tid & 63;
    const int wr = wv >> 1, wc = wv & 1;         // 4x2 wave grid over 256x256
    const int l15 = ln & 15, l4 = ln >> 4;
    const int m0 = by * 256, n0 = bx * 256;
    const int Kc = Kdim / gridDim.z;
    const int kbeg = bz * Kc;
    const int NH = Kc / 32;                      // K-halves; >= 2 always

    f32x4 acc[4][8] = {};

    // Staging: per half, 256x32 tile = 1024 chunks of 16B per matrix;
    // 512 threads x 2 chunks. c = q*512+tid: row = c>>2, ch = c&3;
    // global source chunk = ch ^ ((row>>1)&3); LDS dest linear.
    size_t arow[2], brow[2];
    int lbase[2];
    #pragma unroll
    for (int q = 0; q < 2; ++q) {
        const int c = q * 512 + tid;
        const int row = c >> 2, ch = c & 3;
        const int src = (ch ^ ((row >> 1) & 3)) * 8;
        arow[q] = (size_t)(m0 + row) * Kdim + src;
        brow[q] = (size_t)(n0 + row) * Kdim + src;
        lbase[q] = (q * 512 + wv * 64) * 8;      // elements; wave-uniform base
    }

    // Fragment-read swizzle: (row>>1)&3 == (l15>>1)&3 for every frag row.
    const int koff = ((l4 ^ ((l15 >> 1) & 3))) * 8;

    auto issue = [&](int h) {
        const int s = h & 3;
        const size_t kk = (size_t)(kbeg + h * 32);
        #pragma unroll
        for (int q = 0; q < 2; ++q) {
            gload16(A + arow[q] + kk, &As[s][lbase[q]]);
            gload16(B + brow[q] + kk, &Bs[s][lbase[q]]);
        }
    };

    // Prologue: stage 3 halves ahead (12 wave-loads in flight)
    issue(0);
    if (NH > 1) issue(1);
    if (NH > 2) issue(2);

    for (int h = 0; h < NH; ++h) {
        // Counted wait: only the oldest half must have arrived.
        if (h < NH - 2)       asm volatile("s_waitcnt vmcnt(8)" ::: "memory");
        else if (h == NH - 2) asm volatile("s_waitcnt vmcnt(4)" ::: "memory");
        else                  asm volatile("s_waitcnt vmcnt(0)" ::: "memory");
        __builtin_amdgcn_s_barrier();
        asm volatile("" ::: "memory");

        if (h + 3 < NH) issue(h + 3);            // overwrites slot (h-1)&3: safe

        const int s = h & 3;
        bf16v a[4], b[4];
        #pragma unroll
        for (int i = 0; i < 4; ++i)
            a[i] = *(const bf16v*)&As[s][(wr * 64 + i * 16 + l15) * 32 + koff];
        #pragma unroll
        for (int j = 0; j < 4; ++j)
            b[j] = *(const bf16v*)&Bs[s][(wc * 128 + j * 16 + l15) * 32 + koff];
        __builtin_amdgcn_s_setprio(1);
        #pragma unroll
        for (int i = 0; i < 4; ++i)
            #pragma unroll
            for (int j = 0; j < 4; ++j)
                acc[i][j] = __builtin_amdgcn_mfma_f32_16x16x32_bf16(
                    a[i], b[j], acc[i][j], 0, 0, 0);
        __builtin_amdgcn_s_setprio(0);
        #pragma unroll
        for (int j = 0; j < 4; ++j)
            b[j] = *(const bf16v*)&Bs[s][(wc * 128 + (j + 4) * 16 + l15) * 32 + koff];
        __builtin_amdgcn_s_setprio(1);
        #pragma unroll
        for (int i = 0; i < 4; ++i)
            #pragma unroll
            for (int j = 0; j < 4; ++j)
                acc[i][j + 4] = __builtin_amdgcn_mfma_f32_16x16x32_bf16(
                    a[i], b[j], acc[i][j + 4], 0, 0, 0);
        __builtin_amdgcn_s_setprio(0);
        asm volatile("" ::: "memory");
    }

    // C/D layout: col = lane&15, row = (lane>>4)*4 + reg  [m89-verified]
    #pragma unroll
    for (int i = 0; i < 4; ++i)
        #pragma unroll
        for (int j = 0; j < 8; ++j)
            #pragma unroll
            for (int r = 0; r < 4; ++r) {
                const int gm = m0 + wr * 64 + i * 16 + l4 * 4 + r;
                const int gn = n0 + wc * 128 + j * 16 + l15;
                const size_t off = (size_t)gm * Ndim + gn;
                float v = alpha * acc[i][j][r];
                if (Cp) {
                    Cp[(size_t)bz * Mdim * Ndim + off] = f2bf(v);
                } else {
                    if (Add) v += Add[off];
                    if (Cf) Cf[off] = v;
                    if (Cb) Cb[off] = f2bf(v);
                }
            }
}

// Sum bf16 split-K partials (+f32 Add), write f32 and/or bf16. 8 elems/thread.
__global__ __launch_bounds__(256) void reduce_kb(
    const u16* __restrict__ Cp, int nz, int sz,
    const float* __restrict__ Add, float* __restrict__ Cf, u16* __restrict__ Cb)
{
    const size_t i = ((size_t)blockIdx.x * 256 + threadIdx.x) * 8;
    float s[8] = {};
    for (int z = 0; z < nz; ++z) {
        u16x8 v = *(const u16x8*)(Cp + (size_t)z * sz + i);
        #pragma unroll
        for (int k = 0; k < 8; ++k) s[k] += bf2f(v[k]);
    }
    if (Add) {
        float4 a0 = *(const float4*)(Add + i);
        float4 a1 = *(const float4*)(Add + i + 4);
        s[0] += a0.x; s[1] += a0.y; s[2] += a0.z; s[3] += a0.w;
        s[4] += a1.x; s[5] += a1.y; s[6] += a1.z; s[7] += a1.w;
    }
    if (Cf) {
        *(float4*)(Cf + i)     = make_float4(s[0], s[1], s[2], s[3]);
        *(float4*)(Cf + i + 4) = make_float4(s[4], s[5], s[6], s[7]);
    }
    if (Cb) {
        u16x8 o;
        #pragma unroll
        for (int k = 0; k < 8; ++k) o[k] = f2bf(s[k]);
        *(u16x8*)(Cb + i) = o;
    }
}

// fp32 -> bf16 cast (n4 = n/4 float4 groups)
__global__ __launch_bounds__(256) void cast_bf(const float* __restrict__ in,
                                               u16* __restrict__ out, int n4)
{
    const int i = blockIdx.x * 256 + threadIdx.x;
    if (i >= n4) return;
    float4 v = *(const float4*)(in + (size_t)i * 4);
    ushort4 o; o.x = f2bf(v.x); o.y = f2bf(v.y); o.z = f2bf(v.z); o.w = f2bf(v.w);
    *(ushort4*)(out + (size_t)i * 4) = o;
}

// EstuT[n][j] = Estu[j][n], fp32 -> bf16 (32x32 LDS tile)
__global__ __launch_bounds__(256) void transpose_bf(const float* __restrict__ in,
                                                    u16* __restrict__ out)
{
    __shared__ float tile[32][33];
    const int j0 = blockIdx.x * 32, n0 = blockIdx.y * 32;
    const int tx = threadIdx.x & 31, ty = threadIdx.x >> 5;
    #pragma unroll
    for (int r = 0; r < 4; ++r)
        tile[ty + r * 8][tx] = in[(size_t)(j0 + ty + r * 8) * N_ + n0 + tx];
    __syncthreads();
    #pragma unroll
    for (int r = 0; r < 4; ++r)
        out[(size_t)(n0 + ty + r * 8) * J_ + j0 + tx] = f2bf(tile[tx][ty + r * 8]);
}

// EbT[(c*5+ii)][n] = E[c][n][ii]  bf16  (B-operand for the ywE GEMM)
__global__ __launch_bounds__(256) void build_EbT(const float* __restrict__ E,
                                                 u16* __restrict__ EbT)
{
    const int c = blockIdx.x;
    for (int n = threadIdx.x; n < N_; n += 256) {
        const float* ep = E + (size_t)c * (N_ * M_) + (size_t)n * M_;
        #pragma unroll
        for (int ii = 0; ii < M_; ++ii)
            EbT[(size_t)(c * M_ + ii) * N_ + n] = f2bf(ep[ii]);
    }
}

// Pass 1: segment sums S[seg][j] = sum_{t in seg} phi[t,i]*U[t,c],  j=i*512+c
__global__ __launch_bounds__(256) void scanS(const float* __restrict__ U,
                                             const float* __restrict__ phi,
                                             float* __restrict__ S)
{
    const int j0 = (blockIdx.x * 256 + threadIdx.x) * 2;
    const int seg = blockIdx.y;
    const int i = j0 >> 9, c = j0 & 511;
    float a0 = 0.f, a1 = 0.f;
    const int t0 = seg * SEGLEN;
    for (int t = t0; t < t0 + SEGLEN; ++t) {
        float2 u = *(const float2*)(U + (size_t)t * MC_ + c);
        float ph = phi[t * KF_ + i];
        a0 += ph * u.x; a1 += ph * u.y;
    }
    *(float2*)(S + (size_t)seg * J_ + j0) = make_float2(a0, a1);
}

// Pass 2: exclusive scan over segments
__global__ __launch_bounds__(256) void scanB(const float* __restrict__ S,
                                             float* __restrict__ O)
{
    const int j0 = (blockIdx.x * 256 + threadIdx.x) * 2;
    float o0 = 0.f, o1 = 0.f;
    #pragma unroll
    for (int s = 0; s < NSEG; ++s) {
        *(float2*)(O + (size_t)s * J_ + j0) = make_float2(o0, o1);
        float2 sv = *(const float2*)(S + (size_t)s * J_ + j0);
        o0 += sv.x; o1 += sv.y;
    }
}

// Pass 3: global strict prefix, written directly as bf16 P
__global__ __launch_bounds__(256) void scanC(const float* __restrict__ U,
                                             const float* __restrict__ phi,
                                             const float* __restrict__ O,
                                             u16* __restrict__ P)
{
    const int j0 = (blockIdx.x * 256 + threadIdx.x) * 2;
    const int seg = blockIdx.y;
    const int i = j0 >> 9, c = j0 & 511;
    float2 o = *(const float2*)(O + (size_t)seg * J_ + j0);
    float a0 = o.x, a1 = o.y;
    const int t0 = seg * SEGLEN;
    for (int t = t0; t < t0 + SEGLEN; ++t) {
        ushort2 pv; pv.x = f2bf(a0); pv.y = f2bf(a1);
        *(ushort2*)(P + (size_t)t * J_ + j0) = pv;
        float2 u = *(const float2*)(U + (size_t)t * MC_ + c);
        float ph = phi[t * KF_ + i];
        a0 += ph * u.x; a1 += ph * u.y;
    }
}

// D[t,c] = bias[c] + sum_i ywE[t-4+i][c*5+i]; also writes U^0 = D
__global__ __launch_bounds__(256) void build_D(const float* __restrict__ ywE,
                                               const float* __restrict__ bias,
                                               float* __restrict__ D,
                                               float* __restrict__ U0)
{
    const int idx = blockIdx.x * 256 + threadIdx.x;
    const int t = idx >> 9, c = idx & 511;
    float v = bias[c];
    #pragma unroll
    for (int ii = 0; ii < M_; ++ii) {
        int ts = t - (M_ - 1) + ii;
        if (ts >= 0) v += ywE[(size_t)ts * (MC_ * M_) + c * M_ + ii];
    }
    D[idx] = v;
    U0[idx] = v;
}

// losses[t] = dot(X[t],Y[t]) + dot(U[t],Z[t])
__global__ __launch_bounds__(256) void rowdot(
    const float* __restrict__ X, const float* __restrict__ Y,
    const float* __restrict__ U, const float* __restrict__ Z,
    float* __restrict__ out)
{
    const int t = blockIdx.x;
    float s = 0.f;
    for (int n = threadIdx.x; n < N_; n += 256)
        s += X[(size_t)t * N_ + n] * Y[(size_t)t * N_ + n];
    for (int c = threadIdx.x; c < MC_; c += 256)
        s += U[(size_t)t * MC_ + c] * Z[(size_t)t * MC_ + c];
    __shared__ float red[256];
    red[threadIdx.x] = s;
    __syncthreads();
    for (int off = 128; off > 0; off >>= 1) {
        if (threadIdx.x < off) red[threadIdx.x] += red[threadIdx.x + off];
        __syncthreads();
    }
    if (threadIdx.x == 0) out[t] = red[0];
}

// ---------------------------------------------------------------------------
extern "C" void kernel_launch(void* const* d_in, const int* in_sizes, int n_in,
                              void* d_out, int out_size, void* d_ws, size_t ws_size,
                              hipStream_t stream)
{
    const float* Qm   = (const float*)d_in[2];
    const float* Rm   = (const float*)d_in[3];
    const float* Km   = (const float*)d_in[4];
    const float* Em   = (const float*)d_in[5];
    const float* bias = (const float*)d_in[6];
    const float* Estu = (const float*)d_in[7];   // [J_, N_]
    const float* phi  = (const float*)d_in[8];   // [T, KF]
    const float* w    = (const float*)d_in[9];   // [T, N]
    float* out = (float*)d_out;

    // ---- workspace carve-up: ~134.0 MB total (<= 134.87 proven in round 1)
    char* w8 = (char*)d_ws;
    size_t off = 0;
    auto alloc = [&](size_t bytes) -> void* {
        void* p = w8 + off; off += (bytes + 255) & ~(size_t)255; return p;
    };
    // persistent
    u16*   Pb  = (u16*)  alloc((size_t)T_ * J_ * 2);        // 41.9 MB bf16 prefix P
    u16*   Fb  = (u16*)  alloc((size_t)MC_ * J_ * 2);       // 10.5 MB bf16 F
    float* D   = (float*)alloc((size_t)T_ * MC_ * 4);
    float* U   = (float*)alloc((size_t)T_ * MC_ * 4);
    u16*   Ub  = (u16*)  alloc((size_t)T_ * MC_ * 2);
    float* S   = (float*)alloc((size_t)NSEG * J_ * 4);
    float* O   = (float*)alloc((size_t)NSEG * J_ * 4);
    float* X   = (float*)alloc((size_t)T_ * N_ * 4);
    u16*   Xb  = (u16*)  alloc((size_t)T_ * N_ * 2);
    u16*   Eb  = (u16*)  alloc((size_t)J_ * N_ * 2);        // Estu cast, then EstuT
    u16*   Qb  = (u16*)  alloc((size_t)N_ * N_ * 2);
    u16*   Rb  = (u16*)  alloc((size_t)MC_ * MC_ * 2);
    // transient region B (33.55 MB): phase 1 = {ywE, EbT, Kb, Wb}; later = bf16 split-K partials
    char*  regB = (char*)alloc((size_t)4 * T_ * N_ * 4);    // 33,554,432 B
    float* ywE = (float*)regB;                               // 21.0 MB
    u16*   EbT = (u16*)  (regB + 20971520);                  //  5.2 MB
    u16*   Kb  = (u16*)  (regB + 20971520 + 5242880);        //  1.0 MB
    u16*   Wb  = (u16*)  (regB + 20971520 + 5242880 + 1048576); // 4.2 MB
    u16*   Cp  = (u16*)regB;                                 // bf16 partials (after phase 1)
    u16*   CpP = (u16*)Pb;                                   // partials for F/ywE (z=4: 41.9 MB)
    float* Y   = (float*)Pb;                                 // aliases: Pb dead by then
    float* Z   = (float*)((char*)Pb + (size_t)T_ * N_ * 4);

    dim3 blk(256), blkG(512);

    // Casts to bf16
    cast_bf<<<dim3(MC_ * N_ / 1024), blk, 0, stream>>>(Km, Kb, MC_ * N_ / 4);
    cast_bf<<<dim3(N_ * N_ / 1024), blk, 0, stream>>>(Qm, Qb, N_ * N_ / 4);
    cast_bf<<<dim3(MC_ * MC_ / 1024), blk, 0, stream>>>(Rm, Rb, MC_ * MC_ / 4);
    cast_bf<<<dim3(T_ * N_ / 1024), blk, 0, stream>>>(w, Wb, T_ * N_ / 4);
    cast_bf<<<dim3(J_ * N_ / 1024), blk, 0, stream>>>(Estu, Eb, J_ * N_ / 4);
    build_EbT<<<dim3(MC_), blk, 0, stream>>>(Em, EbT);

    // F = -K @ Estu^T -> bf16 [MC_, J_]   (z=4, Kc=256 -> NH=8; 320 blocks)
    gemm_tn<<<dim3(J_ / 256, MC_ / 256, 4), blkG, 0, stream>>>(
        Kb, Eb, nullptr, nullptr, nullptr, CpP, MC_, J_, N_, -1.0f);
    reduce_kb<<<dim3(MC_ * J_ / 2048), blk, 0, stream>>>(
        CpP, 4, MC_ * J_, nullptr, nullptr, Fb);

    // ywE[t][c*5+ii] = sum_n w[t,n]*E[c,n,ii]  (z=4, NH=8; 320 blocks)
    gemm_tn<<<dim3((MC_ * M_) / 256, T_ / 256, 4), blkG, 0, stream>>>(
        Wb, EbT, nullptr, nullptr, nullptr, CpP, T_, MC_ * M_, N_, 1.0f);
    reduce_kb<<<dim3(T_ * (MC_ * M_) / 2048), blk, 0, stream>>>(
        CpP, 4, T_ * (MC_ * M_), nullptr, ywE, nullptr);
    build_D<<<dim3(T_ * MC_ / 256), blk, 0, stream>>>(ywE, bias, D, U);

    // EstuT overwrites Eb (safe: F-GEMM ordered before on stream)
    transpose_bf<<<dim3(J_ / 32, N_ / 32), blk, 0, stream>>>(Estu, Eb);

    // Neumann iterations: U <- D + F * prefix(U).
    // z=16 -> Kc=640 -> NH=20; 256 blocks (1/CU, 8 waves)
    for (int it = 0; it < NIT; ++it) {
        scanS<<<dim3(J_ / 512, NSEG), blk, 0, stream>>>(U, phi, S);
        scanB<<<dim3(J_ / 512), blk, 0, stream>>>(S, O);
        scanC<<<dim3(J_ / 512, NSEG), blk, 0, stream>>>(U, phi, O, Pb);
        gemm_tn<<<dim3(MC_ / 256, T_ / 256, 16), blkG, 0, stream>>>(
            Pb, Fb, nullptr, nullptr, nullptr, Cp, T_, MC_, J_, 1.0f);
        reduce_kb<<<dim3(T_ * MC_ / 2048), blk, 0, stream>>>(
            Cp, 16, T_ * MC_, D, U, (it == NIT - 1) ? Ub : nullptr);
    }

    // Final prefix, then X = P @ Estu  (z=8 -> Kc=1280 -> NH=40; 256 blocks)
    scanS<<<dim3(J_ / 512, NSEG), blk, 0, stream>>>(U, phi, S);
    scanB<<<dim3(J_ / 512), blk, 0, stream>>>(S, O);
    scanC<<<dim3(J_ / 512, NSEG), blk, 0, stream>>>(U, phi, O, Pb);
    gemm_tn<<<dim3(N_ / 256, T_ / 256, 8), blkG, 0, stream>>>(
        Pb, Eb, nullptr, nullptr, nullptr, Cp, T_, N_, J_, 1.0f);
    reduce_kb<<<dim3(T_ * N_ / 2048), blk, 0, stream>>>(
        Cp, 8, T_ * N_, nullptr, X, Xb);

    // Y = X @ Q (symmetric, z=8, Kc=128 -> NH=4; 256 blocks)
    gemm_tn<<<dim3(N_ / 256, T_ / 256, 8), blkG, 0, stream>>>(
        Xb, Qb, nullptr, nullptr, nullptr, Cp, T_, N_, N_, 1.0f);
    reduce_kb<<<dim3(T_ * N_ / 2048), blk, 0, stream>>>(
        Cp, 8, T_ * N_, nullptr, Y, nullptr);
    // Z = U @ R (symmetric, z=8, Kc=64 -> NH=2; 128 blocks)
    gemm_tn<<<dim3(MC_ / 256, T_ / 256, 8), blkG, 0, stream>>>(
        Ub, Rb, nullptr, nullptr, nullptr, Cp, T_, MC_, MC_, 1.0f);
    reduce_kb<<<dim3(T_ * MC_ / 2048), blk, 0, stream>>>(
        Cp, 8, T_ * MC_, nullptr, Z, nullptr);
    rowdot<<<dim3(T_), blk, 0, stream>>>(X, Y, U, Z, out);
}

// Round 10
// 319.337 us; speedup vs baseline: 1.4222x; 1.4222x over previous
//
#include <hip/hip_runtime.h>

// Problem constants (fixed by the reference)
#define T_    2048
#define N_    1024
#define MC_   512
#define KF_   20
#define M_    5
#define J_    (KF_ * MC_)      // 10240
#define NSEG  16
#define SEGLEN (T_ / NSEG)     // 128
// NIT=1: single Neumann iteration. ||L|| measured ~0.023 (r1-r9 ladder:
// absmax bit-identical 2.0 for NIT=6/4/3/2 -> truncation invisible).
// Dropped term L^2 D ~ 3.7e-4 rms in U -> loss delta ~0.05 typ, <=1.1 worst,
// vs threshold slack 5.08. x-path stays exact w.r.t. U1 (second scan kept).
#define NIT   1

typedef unsigned short u16;
typedef __attribute__((ext_vector_type(8))) __bf16 bf16v;          // MFMA A/B frag
typedef __attribute__((ext_vector_type(4))) float  f32x4;          // MFMA C/D frag
typedef __attribute__((ext_vector_type(8))) unsigned short u16x8;

__device__ inline u16 f2bf(float f) {                      // RNE f32 -> bf16
    unsigned u = __float_as_uint(f);
    u += 0x7fff + ((u >> 16) & 1);
    return (u16)(u >> 16);
}
__device__ inline float bf2f(u16 v) { return __uint_as_float((unsigned)v << 16); }

__device__ inline void gload16(const void* g, void* l) {   // 16B global -> LDS (lane*16 dest)
    __builtin_amdgcn_global_load_lds((const __attribute__((address_space(1))) void*)g,
                                     (__attribute__((address_space(3))) void*)l, 16, 0, 0);
}

// ---------------------------------------------------------------------------
// bf16 MFMA GEMM, TN form: C[m,n] = alpha * sum_k A[m,k]*B[n,k]
// EXACT round-6 configuration — the measured-best GEMM structure across
// rounds 4-9 (r7 vmcnt graft, r8 256^2, r9 deep-ring all regressed vs this;
// matches guide m190/m196/m233: 2-phase + drain barrier is a local optimum
// unless the full fine-interleaved 8-phase schedule is ported exactly).
// 128x128 tile, BK=64, 4 waves; double-buffered LDS, stage-next-early, one
// __syncthreads per K-step (compiler-enforced drain, race-free).
// LDS swizzle: 16B chunk ch (0..7) within each 128B row XORed with (row&7)
// on the GLOBAL SOURCE (LDS dest linear, rule #21) and on the ds_read side;
// conflict-free (r5/r6: SQ_LDS_BANK_CONFLICT == 0).
// Cp set: grid.z splits K (Kdim/gridDim.z % 64 == 0); bf16 partials to Cp[z].
// else: epilogue adds Add (if set), writes Cf (f32) and/or Cb (bf16).
// Block ids chunk-swizzled across 8 XCDs (bijective; total%8==0 always here).
// ---------------------------------------------------------------------------
__global__ __launch_bounds__(256) void gemm_tn(
    const u16* __restrict__ A, const u16* __restrict__ B,
    const float* __restrict__ Add, float* __restrict__ Cf,
    u16* __restrict__ Cb, u16* __restrict__ Cp,
    int Mdim, int Ndim, int Kdim, float alpha)
{
    __shared__ u16 As[2][128 * 64];   // 16 KB per buffer
    __shared__ u16 Bs[2][128 * 64];

    // ---- XCD chunk swizzle (T1, bijective since total%8==0) ----
    const int gx = gridDim.x, gy = gridDim.y;
    const int total = gx * gy * gridDim.z;
    int lin = blockIdx.x + gx * (blockIdx.y + gy * blockIdx.z);
    lin = (lin & 7) * (total >> 3) + (lin >> 3);
    int bx, by, bz;
    if (gx <= gy) { bx = lin % gx; int r = lin / gx; by = r % gy; bz = r / gy; }
    else          { by = lin % gy; int r = lin / gy; bx = r % gx; bz = r / gx; }

    const int tid = threadIdx.x;
    const int wv = tid >> 6, ln = tid & 63;
    const int wr = wv >> 1, wc = wv & 1;         // wave quadrant
    const int l15 = ln & 15, l4 = ln >> 4;
    const int m0 = by * 128, n0 = bx * 128;
    const int Kc = Kdim / gridDim.z;
    const int kbeg = bz * Kc;
    const int nt = Kc / 64;

    f32x4 acc[4][4] = {};

    // Staging: 128x64 tile = 1024 chunks of 16B; thread handles 4 chunks per
    // matrix: c_q = q*256 + tid. row = c>>3, ch = c&7; global source chunk is
    // ch ^ (row&7); LDS dest linear (wave-uniform base + lane*16).
    size_t arow[4], brow[4];
    int lbase[4];
    #pragma unroll
    for (int q = 0; q < 4; ++q) {
        const int c = q * 256 + tid;
        const int row = c >> 3, ch = c & 7;
        const int src = ((ch ^ (row & 7)) * 8);
        arow[q] = (size_t)(m0 + row) * Kdim + src;
        brow[q] = (size_t)(n0 + row) * Kdim + src;
        lbase[q] = (q * 256 + wv * 64) * 8;      // elements; wave-uniform
    }

    // Fragment-read swizzle: row&7 == l15&7 for every frag row.
    const int fsw = l15 & 7;

    // Prologue: stage tile 0
    #pragma unroll
    for (int q = 0; q < 4; ++q) {
        gload16(A + arow[q] + kbeg, &As[0][lbase[q]]);
        gload16(B + brow[q] + kbeg, &Bs[0][lbase[q]]);
    }
    __syncthreads();

    int cur = 0;
    for (int t = 0; t < nt; ++t) {
        if (t + 1 < nt) {          // stage next tile early (hidden under MFMA)
            const int kk = kbeg + (t + 1) * 64;
            #pragma unroll
            for (int q = 0; q < 4; ++q) {
                gload16(A + arow[q] + kk, &As[cur ^ 1][lbase[q]]);
                gload16(B + brow[q] + kk, &Bs[cur ^ 1][lbase[q]]);
            }
        }
        bf16v a[4][2], b[4][2];
        #pragma unroll
        for (int i = 0; i < 4; ++i)
            #pragma unroll
            for (int s = 0; s < 2; ++s) {
                const int ch = ((s * 4 + l4) ^ fsw) * 8;
                a[i][s] = *(const bf16v*)&As[cur][(wr * 64 + i * 16 + l15) * 64 + ch];
                b[i][s] = *(const bf16v*)&Bs[cur][(wc * 64 + i * 16 + l15) * 64 + ch];
            }
        #pragma unroll
        for (int s = 0; s < 2; ++s)
            #pragma unroll
            for (int i = 0; i < 4; ++i)
                #pragma unroll
                for (int j = 0; j < 4; ++j)
                    acc[i][j] = __builtin_amdgcn_mfma_f32_16x16x32_bf16(
                        a[i][s], b[j][s], acc[i][j], 0, 0, 0);
        __syncthreads();   // drains staging vmcnt; protects buf[cur] for next stage
        cur ^= 1;
    }

    // C/D layout: col = lane&15, row = (lane>>4)*4 + reg  [m89-verified]
    #pragma unroll
    for (int i = 0; i < 4; ++i)
        #pragma unroll
        for (int j = 0; j < 4; ++j)
            #pragma unroll
            for (int r = 0; r < 4; ++r) {
                const int gm = m0 + wr * 64 + i * 16 + l4 * 4 + r;
                const int gn = n0 + wc * 64 + j * 16 + l15;
                const size_t off = (size_t)gm * Ndim + gn;
                float v = alpha * acc[i][j][r];
                if (Cp) {
                    Cp[(size_t)bz * Mdim * Ndim + off] = f2bf(v);
                } else {
                    if (Add) v += Add[off];
                    if (Cf) Cf[off] = v;
                    if (Cb) Cb[off] = f2bf(v);
                }
            }
}

// Sum bf16 split-K partials (+f32 Add), write f32 and/or bf16. 8 elems/thread.
__global__ __launch_bounds__(256) void reduce_kb(
    const u16* __restrict__ Cp, int nz, int sz,
    const float* __restrict__ Add, float* __restrict__ Cf, u16* __restrict__ Cb)
{
    const size_t i = ((size_t)blockIdx.x * 256 + threadIdx.x) * 8;
    float s[8] = {};
    for (int z = 0; z < nz; ++z) {
        u16x8 v = *(const u16x8*)(Cp + (size_t)z * sz + i);
        #pragma unroll
        for (int k = 0; k < 8; ++k) s[k] += bf2f(v[k]);
    }
    if (Add) {
        float4 a0 = *(const float4*)(Add + i);
        float4 a1 = *(const float4*)(Add + i + 4);
        s[0] += a0.x; s[1] += a0.y; s[2] += a0.z; s[3] += a0.w;
        s[4] += a1.x; s[5] += a1.y; s[6] += a1.z; s[7] += a1.w;
    }
    if (Cf) {
        *(float4*)(Cf + i)     = make_float4(s[0], s[1], s[2], s[3]);
        *(float4*)(Cf + i + 4) = make_float4(s[4], s[5], s[6], s[7]);
    }
    if (Cb) {
        u16x8 o;
        #pragma unroll
        for (int k = 0; k < 8; ++k) o[k] = f2bf(s[k]);
        *(u16x8*)(Cb + i) = o;
    }
}

// fp32 -> bf16 cast (n4 = n/4 float4 groups)
__global__ __launch_bounds__(256) void cast_bf(const float* __restrict__ in,
                                               u16* __restrict__ out, int n4)
{
    const int i = blockIdx.x * 256 + threadIdx.x;
    if (i >= n4) return;
    float4 v = *(const float4*)(in + (size_t)i * 4);
    ushort4 o; o.x = f2bf(v.x); o.y = f2bf(v.y); o.z = f2bf(v.z); o.w = f2bf(v.w);
    *(ushort4*)(out + (size_t)i * 4) = o;
}

// EstuT[n][j] = Estu[j][n], fp32 -> bf16 (32x32 LDS tile)
__global__ __launch_bounds__(256) void transpose_bf(const float* __restrict__ in,
                                                    u16* __restrict__ out)
{
    __shared__ float tile[32][33];
    const int j0 = blockIdx.x * 32, n0 = blockIdx.y * 32;
    const int tx = threadIdx.x & 31, ty = threadIdx.x >> 5;
    #pragma unroll
    for (int r = 0; r < 4; ++r)
        tile[ty + r * 8][tx] = in[(size_t)(j0 + ty + r * 8) * N_ + n0 + tx];
    __syncthreads();
    #pragma unroll
    for (int r = 0; r < 4; ++r)
        out[(size_t)(n0 + ty + r * 8) * J_ + j0 + tx] = f2bf(tile[tx][ty + r * 8]);
}

// EbT[(c*5+ii)][n] = E[c][n][ii]  bf16  (B-operand for the ywE GEMM)
__global__ __launch_bounds__(256) void build_EbT(const float* __restrict__ E,
                                                 u16* __restrict__ EbT)
{
    const int c = blockIdx.x;
    for (int n = threadIdx.x; n < N_; n += 256) {
        const float* ep = E + (size_t)c * (N_ * M_) + (size_t)n * M_;
        #pragma unroll
        for (int ii = 0; ii < M_; ++ii)
            EbT[(size_t)(c * M_ + ii) * N_ + n] = f2bf(ep[ii]);
    }
}

// Pass 1: segment sums S[seg][j] = sum_{t in seg} phi[t,i]*U[t,c],  j=i*512+c
__global__ __launch_bounds__(256) void scanS(const float* __restrict__ U,
                                             const float* __restrict__ phi,
                                             float* __restrict__ S)
{
    const int j0 = (blockIdx.x * 256 + threadIdx.x) * 2;
    const int seg = blockIdx.y;
    const int i = j0 >> 9, c = j0 & 511;
    float a0 = 0.f, a1 = 0.f;
    const int t0 = seg * SEGLEN;
    for (int t = t0; t < t0 + SEGLEN; ++t) {
        float2 u = *(const float2*)(U + (size_t)t * MC_ + c);
        float ph = phi[t * KF_ + i];
        a0 += ph * u.x; a1 += ph * u.y;
    }
    *(float2*)(S + (size_t)seg * J_ + j0) = make_float2(a0, a1);
}

// Pass 2: exclusive scan over segments
__global__ __launch_bounds__(256) void scanB(const float* __restrict__ S,
                                             float* __restrict__ O)
{
    const int j0 = (blockIdx.x * 256 + threadIdx.x) * 2;
    float o0 = 0.f, o1 = 0.f;
    #pragma unroll
    for (int s = 0; s < NSEG; ++s) {
        *(float2*)(O + (size_t)s * J_ + j0) = make_float2(o0, o1);
        float2 sv = *(const float2*)(S + (size_t)s * J_ + j0);
        o0 += sv.x; o1 += sv.y;
    }
}

// Pass 3: global strict prefix, written directly as bf16 P
__global__ __launch_bounds__(256) void scanC(const float* __restrict__ U,
                                             const float* __restrict__ phi,
                                             const float* __restrict__ O,
                                             u16* __restrict__ P)
{
    const int j0 = (blockIdx.x * 256 + threadIdx.x) * 2;
    const int seg = blockIdx.y;
    const int i = j0 >> 9, c = j0 & 511;
    float2 o = *(const float2*)(O + (size_t)seg * J_ + j0);
    float a0 = o.x, a1 = o.y;
    const int t0 = seg * SEGLEN;
    for (int t = t0; t < t0 + SEGLEN; ++t) {
        ushort2 pv; pv.x = f2bf(a0); pv.y = f2bf(a1);
        *(ushort2*)(P + (size_t)t * J_ + j0) = pv;
        float2 u = *(const float2*)(U + (size_t)t * MC_ + c);
        float ph = phi[t * KF_ + i];
        a0 += ph * u.x; a1 += ph * u.y;
    }
}

// D[t,c] = bias[c] + sum_i ywE[t-4+i][c*5+i]; also writes U^0 = D
__global__ __launch_bounds__(256) void build_D(const float* __restrict__ ywE,
                                               const float* __restrict__ bias,
                                               float* __restrict__ D,
                                               float* __restrict__ U0)
{
    const int idx = blockIdx.x * 256 + threadIdx.x;
    const int t = idx >> 9, c = idx & 511;
    float v = bias[c];
    #pragma unroll
    for (int ii = 0; ii < M_; ++ii) {
        int ts = t - (M_ - 1) + ii;
        if (ts >= 0) v += ywE[(size_t)ts * (MC_ * M_) + c * M_ + ii];
    }
    D[idx] = v;
    U0[idx] = v;
}

// losses[t] = dot(X[t],Y[t]) + dot(U[t],Z[t])
__global__ __launch_bounds__(256) void rowdot(
    const float* __restrict__ X, const float* __restrict__ Y,
    const float* __restrict__ U, const float* __restrict__ Z,
    float* __restrict__ out)
{
    const int t = blockIdx.x;
    float s = 0.f;
    for (int n = threadIdx.x; n < N_; n += 256)
        s += X[(size_t)t * N_ + n] * Y[(size_t)t * N_ + n];
    for (int c = threadIdx.x; c < MC_; c += 256)
        s += U[(size_t)t * MC_ + c] * Z[(size_t)t * MC_ + c];
    __shared__ float red[256];
    red[threadIdx.x] = s;
    __syncthreads();
    for (int off = 128; off > 0; off >>= 1) {
        if (threadIdx.x < off) red[threadIdx.x] += red[threadIdx.x + off];
        __syncthreads();
    }
    if (threadIdx.x == 0) out[t] = red[0];
}

// ---------------------------------------------------------------------------
extern "C" void kernel_launch(void* const* d_in, const int* in_sizes, int n_in,
                              void* d_out, int out_size, void* d_ws, size_t ws_size,
                              hipStream_t stream)
{
    const float* Qm   = (const float*)d_in[2];
    const float* Rm   = (const float*)d_in[3];
    const float* Km   = (const float*)d_in[4];
    const float* Em   = (const float*)d_in[5];
    const float* bias = (const float*)d_in[6];
    const float* Estu = (const float*)d_in[7];   // [J_, N_]
    const float* phi  = (const float*)d_in[8];   // [T, KF]
    const float* w    = (const float*)d_in[9];   // [T, N]
    float* out = (float*)d_out;

    // ---- workspace carve-up: ~134.0 MB total (<= 134.87 proven in round 1)
    char* w8 = (char*)d_ws;
    size_t off = 0;
    auto alloc = [&](size_t bytes) -> void* {
        void* p = w8 + off; off += (bytes + 255) & ~(size_t)255; return p;
    };
    // persistent
    u16*   Pb  = (u16*)  alloc((size_t)T_ * J_ * 2);        // 41.9 MB bf16 prefix P
    u16*   Fb  = (u16*)  alloc((size_t)MC_ * J_ * 2);       // 10.5 MB bf16 F
    float* D   = (float*)alloc((size_t)T_ * MC_ * 4);
    float* U   = (float*)alloc((size_t)T_ * MC_ * 4);
    u16*   Ub  = (u16*)  alloc((size_t)T_ * MC_ * 2);
    float* S   = (float*)alloc((size_t)NSEG * J_ * 4);
    float* O   = (float*)alloc((size_t)NSEG * J_ * 4);
    float* X   = (float*)alloc((size_t)T_ * N_ * 4);
    u16*   Xb  = (u16*)  alloc((size_t)T_ * N_ * 2);
    u16*   Eb  = (u16*)  alloc((size_t)J_ * N_ * 2);        // Estu cast, then EstuT
    u16*   Qb  = (u16*)  alloc((size_t)N_ * N_ * 2);
    u16*   Rb  = (u16*)  alloc((size_t)MC_ * MC_ * 2);
    // transient region B (33.55 MB): phase 1 = {ywE, EbT, Kb, Wb}; later = bf16 split-K partials
    char*  regB = (char*)alloc((size_t)4 * T_ * N_ * 4);    // 33,554,432 B
    float* ywE = (float*)regB;                               // 21.0 MB
    u16*   EbT = (u16*)  (regB + 20971520);                  //  5.2 MB
    u16*   Kb  = (u16*)  (regB + 20971520 + 5242880);        //  1.0 MB
    u16*   Wb  = (u16*)  (regB + 20971520 + 5242880 + 1048576); // 4.2 MB
    u16*   Cp  = (u16*)regB;                                 // bf16 partials (after phase 1)
    u16*   CpP = (u16*)Pb;                                   // partials for F/ywE (Pb free then)
    float* Y   = (float*)Pb;                                 // aliases: Pb dead by then
    float* Z   = (float*)((char*)Pb + (size_t)T_ * N_ * 4);

    dim3 blk(256);

    // Casts to bf16
    cast_bf<<<dim3(MC_ * N_ / 1024), blk, 0, stream>>>(Km, Kb, MC_ * N_ / 4);
    cast_bf<<<dim3(N_ * N_ / 1024), blk, 0, stream>>>(Qm, Qb, N_ * N_ / 4);
    cast_bf<<<dim3(MC_ * MC_ / 1024), blk, 0, stream>>>(Rm, Rb, MC_ * MC_ / 4);
    cast_bf<<<dim3(T_ * N_ / 1024), blk, 0, stream>>>(w, Wb, T_ * N_ / 4);
    cast_bf<<<dim3(J_ * N_ / 1024), blk, 0, stream>>>(Estu, Eb, J_ * N_ / 4);
    build_EbT<<<dim3(MC_), blk, 0, stream>>>(Em, EbT);

    // F = -K @ Estu^T -> bf16 [MC_, J_]   (z=2, Kc=512=8 steps; 640 blocks)
    gemm_tn<<<dim3(J_ / 128, MC_ / 128, 2), blk, 0, stream>>>(
        Kb, Eb, nullptr, nullptr, nullptr, CpP, MC_, J_, N_, -1.0f);
    reduce_kb<<<dim3(MC_ * J_ / 2048), blk, 0, stream>>>(
        CpP, 2, MC_ * J_, nullptr, nullptr, Fb);

    // ywE[t][c*5+ii] = sum_n w[t,n]*E[c,n,ii]  (z=2; 640 blocks)
    gemm_tn<<<dim3((MC_ * M_) / 128, T_ / 128, 2), blk, 0, stream>>>(
        Wb, EbT, nullptr, nullptr, nullptr, CpP, T_, MC_ * M_, N_, 1.0f);
    reduce_kb<<<dim3(T_ * (MC_ * M_) / 2048), blk, 0, stream>>>(
        CpP, 2, T_ * (MC_ * M_), nullptr, ywE, nullptr);
    build_D<<<dim3(T_ * MC_ / 256), blk, 0, stream>>>(ywE, bias, D, U);

    // EstuT overwrites Eb (safe: F-GEMM ordered before on stream)
    transpose_bf<<<dim3(J_ / 32, N_ / 32), blk, 0, stream>>>(Estu, Eb);

    // Single Neumann iteration: U1 <- D + F * prefix(D).
    // z=16 -> Kc=640=10 steps; 1024 blocks (r6-proven config)
    for (int it = 0; it < NIT; ++it) {
        scanS<<<dim3(J_ / 512, NSEG), blk, 0, stream>>>(U, phi, S);
        scanB<<<dim3(J_ / 512), blk, 0, stream>>>(S, O);
        scanC<<<dim3(J_ / 512, NSEG), blk, 0, stream>>>(U, phi, O, Pb);
        gemm_tn<<<dim3(MC_ / 128, T_ / 128, 16), blk, 0, stream>>>(
            Pb, Fb, nullptr, nullptr, nullptr, Cp, T_, MC_, J_, 1.0f);
        reduce_kb<<<dim3(T_ * MC_ / 2048), blk, 0, stream>>>(
            Cp, 16, T_ * MC_, D, U, (it == NIT - 1) ? Ub : nullptr);
    }

    // Final prefix on U1, then X = P @ Estu  (z=8 -> Kc=1280=20 steps; 1024 blocks)
    scanS<<<dim3(J_ / 512, NSEG), blk, 0, stream>>>(U, phi, S);
    scanB<<<dim3(J_ / 512), blk, 0, stream>>>(S, O);
    scanC<<<dim3(J_ / 512, NSEG), blk, 0, stream>>>(U, phi, O, Pb);
    gemm_tn<<<dim3(N_ / 128, T_ / 128, 8), blk, 0, stream>>>(
        Pb, Eb, nullptr, nullptr, nullptr, Cp, T_, N_, J_, 1.0f);
    reduce_kb<<<dim3(T_ * N_ / 2048), blk, 0, stream>>>(
        Cp, 8, T_ * N_, nullptr, X, Xb);

    // Y = X @ Q (symmetric, z=4, Kc=256=4 steps, 512 blocks)
    gemm_tn<<<dim3(N_ / 128, T_ / 128, 4), blk, 0, stream>>>(
        Xb, Qb, nullptr, nullptr, nullptr, Cp, T_, N_, N_, 1.0f);
    reduce_kb<<<dim3(T_ * N_ / 2048), blk, 0, stream>>>(
        Cp, 4, T_ * N_, nullptr, Y, nullptr);
    // Z = U @ R (symmetric, z=4, Kc=128=2 steps, 256 blocks)
    gemm_tn<<<dim3(MC_ / 128, T_ / 128, 4), blk, 0, stream>>>(
        Ub, Rb, nullptr, nullptr, nullptr, Cp, T_, MC_, MC_, 1.0f);
    reduce_kb<<<dim3(T_ * MC_ / 2048), blk, 0, stream>>>(
        Cp, 4, T_ * MC_, nullptr, Z, nullptr);
    rowdot<<<dim3(T_), blk, 0, stream>>>(X, Y, U, Z, out);
}